// Round 7
// baseline (887.662 us; speedup 1.0000x reference)
//
#include <hip/hip_runtime.h>
#include <math.h>

// GAU block. N=8, S=2048, D=768, DK=128, 2D=1536. NS=16384 rows.
// Round 13: two targeted levers on the 718.9us round-12 baseline (PV GEMM is
// the #1 dispatch: 147us, FETCH 286MB vs 162MB ideal, Occupancy 30.5%).
//  (a) 2D XCD chunking: grid (12,16) previously chunked 1D as 2by x 12bx
//      per XCD -> B working set 6MB > 4MB L2 -> Vt re-fetch ~2.6x. Now each
//      XCD gets a (cx x cy) sub-rectangle (PV: 6bx x 4by = 5MB working set).
//  (b) MW=5 on PV and QK (grids 1536/2048 blocks saturate the chip; VGPR=60
//      is in the 8-waves/SIMD regime so LDS 32KB -> 5 blocks/CU is the cap;
//      MW=4 under-asked).
// All arithmetic bitwise-identical to round 12.

typedef __bf16 bf16x8 __attribute__((ext_vector_type(8)));
typedef float  f32x4  __attribute__((ext_vector_type(4)));

__device__ __forceinline__ float silu_f(float v) { return v / (1.0f + __expf(-v)); }
__device__ __forceinline__ float sigmoid_f(float v) { return 1.0f / (1.0f + __expf(-v)); }

__device__ __forceinline__ unsigned short f2bf(float f) {
    union { float f; unsigned u; } v; v.f = f;
    unsigned r = v.u + 0x7fff + ((v.u >> 16) & 1);
    return (unsigned short)(r >> 16);
}
__device__ __forceinline__ float bf2f(unsigned short h) {
    union { unsigned u; float f; } v; v.u = ((unsigned)h) << 16; return v.f;
}

__device__ __forceinline__ void gload_lds16(const void* g, void* l) {
    __builtin_amdgcn_global_load_lds((const __attribute__((address_space(1))) char*)g,
                                     (__attribute__((address_space(3))) char*)l, 16, 0, 0);
}

// XCD-aware 2D-chunk bijective swizzle. Original flat index o: XCD = o&7
// (HW round-robin). XCD k owns a (cx x cy) tile-rectangle of the grid,
// cy = (gx*gy/8)/cx; requires cx | gx and cy | gy (true for every launch
// here). Round-8/9 evidence: -21..27% FETCH on PV from 1D chunking; 2D
// shrinks the per-XCD working set further (PV: 7MB -> 5MB vs 4MB L2).
__device__ __forceinline__ void xcd_swizzle(int& bx, int& by, int cx) {
    const int gx = gridDim.x;
    const int o  = by * gx + bx;
    const int c  = (gx * (int)gridDim.y) >> 3;  // blocks per XCD
    const int k  = o & 7;                       // XCD id
    const int j  = o >> 3;                      // ordinal within XCD
    const int nkx = gx / cx;                    // chunk columns
    const int cy  = c / cx;
    bx = (k % nkx) * cx + (j % cx);
    by = (k / nkx) * cy + (j / cx);
}

// ---------------------------------------------------------------------------
// bf16 MFMA GEMM: acc[M,N] = A[M,K] @ Bt[N,K]^T (+2nd pass if DUAL).
// 128x128 tile, BK=64, 256 thr / 4 waves 2x2, each wave 4x4 of 16x16x32.
// LDS rows hold 8 16B slots, stored at slot p = s ^ (r&7) -> 2-way reads.
// MW = min waves per EU (for 256-thr blocks == blocks/CU requested).
// Epilogues: 0 PV / 1 QK / 2 BIAS / 6 OUT / 7 GATE / 8 UVZ (see r12 notes).
// ---------------------------------------------------------------------------
template <int EPI, bool DUAL, int MW>
__global__ __launch_bounds__(256, MW) void mfma_gemm(
    const unsigned short* __restrict__ A,  int lda, long sA,
    const unsigned short* __restrict__ Bt, int ldb, long sB,
    const unsigned short* __restrict__ A2,
    const unsigned short* __restrict__ Bt2,
    const float* __restrict__ bias,
    const float* __restrict__ bias2,
    const float* __restrict__ aux, long sAux,
    float* __restrict__ aux2,
    void* __restrict__ P0, long sP0,
    void* __restrict__ P1,
    int N, int K, int swz_cx)
{
    __shared__ unsigned short As[128 * 64];
    __shared__ unsigned short Bs[128 * 64];
    const int tid  = threadIdx.x;
    const int lane = tid & 63;
    const int wave = tid >> 6;
    const int z    = blockIdx.z;
    int bx = blockIdx.x, by = blockIdx.y;
    xcd_swizzle(bx, by, swz_cx);
    const int row0 = by * 128;
    const int col0 = bx * 128;

    int c_r[4], c_g[4];
    unsigned short* alp[4];
    unsigned short* blp[4];
#pragma unroll
    for (int ci = 0; ci < 4; ++ci) {
        const int c = ci * 256 + tid;
        const int r = c >> 3;
        c_r[ci] = r;
        c_g[ci] = (c & 7) ^ (r & 7);   // global slot fetched into LDS pos c
        alp[ci] = &As[c * 8];
        blp[ci] = &Bs[c * 8];
    }

    const int wr = (wave >> 1) * 64;
    const int wc = (wave & 1) * 64;
    const int fm  = lane & 15;
    const int kbi = lane >> 4;
    const int er  = kbi * 4;

    int aoff[2][4], boff[2][4];
#pragma unroll
    for (int b = 0; b < 2; ++b)
#pragma unroll
        for (int i = 0; i < 4; ++i) {
            const int r = wr + i * 16 + fm;
            aoff[b][i] = r * 64 + (((b * 4 + kbi) ^ (r & 7)) * 8);
            const int n = wc + i * 16 + fm;
            boff[b][i] = n * 64 + (((b * 4 + kbi) ^ (n & 7)) * 8);
        }

    f32x4 acc[4][4];
#pragma unroll
    for (int i = 0; i < 4; ++i)
#pragma unroll
        for (int j = 0; j < 4; ++j) acc[i][j] = (f32x4){0.f, 0.f, 0.f, 0.f};

    const int npass = DUAL ? 2 : 1;
    for (int pass = 0; pass < npass; ++pass) {
        const unsigned short* Ab = (pass ? A2  : A)  + (size_t)z * sA;
        const unsigned short* Bb = (pass ? Bt2 : Bt) + (size_t)z * sB;
        const unsigned short* ag[4];
        const unsigned short* bg[4];
#pragma unroll
        for (int ci = 0; ci < 4; ++ci) {
            ag[ci] = Ab + (size_t)(row0 + c_r[ci]) * lda + c_g[ci] * 8;
            bg[ci] = Bb + (size_t)(col0 + c_r[ci]) * ldb + c_g[ci] * 8;
        }
        for (int k0 = 0; k0 < K; k0 += 64) {
#pragma unroll
            for (int ci = 0; ci < 4; ++ci) { gload_lds16(ag[ci], alp[ci]); ag[ci] += 64; }
#pragma unroll
            for (int ci = 0; ci < 4; ++ci) { gload_lds16(bg[ci], blp[ci]); bg[ci] += 64; }
            __syncthreads();
#pragma unroll
            for (int b = 0; b < 2; ++b) {
                bf16x8 a[4], bb[4];
#pragma unroll
                for (int i = 0; i < 4; ++i) a[i]  = *(const bf16x8*)&As[aoff[b][i]];
#pragma unroll
                for (int j = 0; j < 4; ++j) bb[j] = *(const bf16x8*)&Bs[boff[b][j]];
#pragma unroll
                for (int i = 0; i < 4; ++i)
#pragma unroll
                    for (int j = 0; j < 4; ++j)
                        acc[i][j] = __builtin_amdgcn_mfma_f32_16x16x32_bf16(
                            a[i], bb[j], acc[i][j], 0, 0, 0);
            }
            __syncthreads();
        }
    }

    if (EPI == 0) {
        unsigned short* Ub = (unsigned short*)P0 + (size_t)z * sP0;
        const float* inv = aux2 + (z << 11);
#pragma unroll
        for (int i = 0; i < 4; ++i)
#pragma unroll
            for (int j = 0; j < 4; ++j) {
                const int m0 = row0 + wr + i * 16 + er;
                const int n  = col0 + wc + j * 16 + fm;
#pragma unroll
                for (int reg = 0; reg < 4; ++reg) {
                    const size_t idx = (size_t)(m0 + reg) * N + n;
                    Ub[idx] = f2bf(acc[i][j][reg] * inv[m0 + reg] * bf2f(Ub[idx]));
                }
            }
    } else if (EPI == 1) {
        const float* qb = aux + (size_t)z * sAux;
        unsigned short* Eb = (unsigned short*)P0 + (size_t)z * sP0;
#pragma unroll
        for (int i = 0; i < 4; ++i) {
            float rs[4] = {0.f, 0.f, 0.f, 0.f};
#pragma unroll
            for (int j = 0; j < 4; ++j) {
                const int n = col0 + wc + j * 16 + fm;
#pragma unroll
                for (int reg = 0; reg < 4; ++reg) {
                    const int m = row0 + wr + i * 16 + er + reg;
                    int d = n - m;
                    d = d < -5 ? -5 : (d > 5 ? 5 : d);
                    const float v =
                        __expf((acc[i][j][reg] + qb[m * 11 + d + 5]) * 0.0625f);
                    const unsigned short h = f2bf(v);
                    Eb[(size_t)m * N + n] = h;
                    rs[reg] += bf2f(h);
                }
            }
#pragma unroll
            for (int reg = 0; reg < 4; ++reg) {
                float s = rs[reg];
                s += __shfl_xor(s, 1); s += __shfl_xor(s, 2);
                s += __shfl_xor(s, 4); s += __shfl_xor(s, 8);
                if (fm == 0) {
                    const int m = row0 + wr + i * 16 + er + reg;
                    aux2[((size_t)(z * 2048 + m)) * 32 + bx * 2 + (wave & 1)] = s;
                }
            }
        }
    } else if (EPI == 2) {
        unsigned short* Cb = (unsigned short*)P0;
#pragma unroll
        for (int j = 0; j < 4; ++j) {
            const int n = col0 + wc + j * 16 + fm;
            const float bb = bias[n];
#pragma unroll
            for (int i = 0; i < 4; ++i) {
                const int m0 = row0 + wr + i * 16 + er;
#pragma unroll
                for (int reg = 0; reg < 4; ++reg)
                    Cb[(size_t)(m0 + reg) * N + n] = f2bf(acc[i][j][reg] + bb);
            }
        }
    } else if (EPI == 6) {
        float* Of = (float*)P0;
        unsigned short* Ob = (unsigned short*)P1;
#pragma unroll
        for (int j = 0; j < 4; ++j) {
            const int n = col0 + wc + j * 16 + fm;
            const float bb = bias[n];
#pragma unroll
            for (int i = 0; i < 4; ++i) {
                const int m0 = row0 + wr + i * 16 + er;
#pragma unroll
                for (int reg = 0; reg < 4; ++reg) {
                    const float v = acc[i][j][reg] + bb;
                    const size_t idx = (size_t)(m0 + reg) * N + n;
                    Of[idx] = v;
                    Ob[idx] = f2bf(v);
                }
            }
        }
    } else if (EPI == 7) {
        float* Of = (float*)P0;
        const float* res = aux;
#pragma unroll
        for (int j = 0; j < 4; ++j) {
            const int n = col0 + wc + j * 16 + fm;
            const float bb = bias[n];
#pragma unroll
            for (int i = 0; i < 4; ++i) {
                const int m0 = row0 + wr + i * 16 + er;
#pragma unroll
                for (int reg = 0; reg < 4; ++reg) {
                    const float g = sigmoid_f(acc[i][j][reg] + bb);
                    const size_t idx = (size_t)(m0 + reg) * N + n;
                    Of[idx] = g * Of[idx] + (1.0f - g) * res[idx];
                }
            }
        }
    } else {  // EPI 8: merged U | Vt | Z — block-uniform on bx
        if (bx < 12) {
            unsigned short* Ub = (unsigned short*)P0;
#pragma unroll
            for (int j = 0; j < 4; ++j) {
                const int n = col0 + wc + j * 16 + fm;
                const float bb = bias[n];
#pragma unroll
                for (int i = 0; i < 4; ++i) {
                    const int m0 = row0 + wr + i * 16 + er;
#pragma unroll
                    for (int reg = 0; reg < 4; ++reg)
                        Ub[(size_t)(m0 + reg) * 1536 + n] =
                            f2bf(silu_f(acc[i][j][reg] + bb));
                }
            }
        } else if (bx < 24) {
            unsigned short* Vt = (unsigned short*)P1;
#pragma unroll
            for (int j = 0; j < 4; ++j) {
                const int n = col0 + wc + j * 16 + fm;
                const float bb = bias2[n - 1536];
#pragma unroll
                for (int i = 0; i < 4; ++i) {
                    const int m0 = row0 + wr + i * 16 + er;
                    const int bat = m0 >> 11;
                    const int sl  = m0 & 2047;
                    unsigned short t[4];
#pragma unroll
                    for (int reg = 0; reg < 4; ++reg)
                        t[reg] = f2bf(silu_f(acc[i][j][reg] + bb));
                    *(ushort4*)(Vt + (size_t)bat * 1536 * 2048
                                + (size_t)(n - 1536) * 2048 + sl) = *(const ushort4*)t;
                }
            }
        } else {
            float* Zf = aux2;
#pragma unroll
            for (int j = 0; j < 4; ++j) {
                const int n = col0 + wc + j * 16 + fm;
                const float bb = aux[n - 3072];
#pragma unroll
                for (int i = 0; i < 4; ++i) {
                    const int m0 = row0 + wr + i * 16 + er;
#pragma unroll
                    for (int reg = 0; reg < 4; ++reg)
                        Zf[(size_t)(m0 + reg) * 128 + (n - 3072)] =
                            silu_f(acc[i][j][reg] + bb);
                }
            }
        }
    }
}

// rowsum inverse: inv[r] = 1 / sum_k part[r][k], r in [0,16384)
__global__ __launch_bounds__(256) void reduce_inv(
    const float* __restrict__ part, float* __restrict__ inv)
{
    const int r = blockIdx.x * 256 + threadIdx.x;
    const float4* p = (const float4*)(part + (size_t)r * 32);
    float s = 0.f;
#pragma unroll
    for (int k = 0; k < 8; ++k) {
        float4 v = p[k];
        s += v.x + v.y + v.z + v.w;
    }
    inv[r] = 1.0f / s;
}

// All input prep in one launch. Flat grid:
// [0,12288)      : seq fp32 -> bf16 (4 elems/thread)
// [12288,12864)  : W_init -> Wit        (768x768)
// [12864,14016)  : W_u    -> Wuvzt      (768x1536)
// [14016,15168)  : W_v    -> Wuvzt+1536*768
// [15168,15264)  : W_z    -> Wuvzt+3072*768 (768x128)
// [15264,16416)  : W_out  -> Wot        (1536x768)
// [16416,17568)  : W_gate -> Wgt        (1536x768)
__global__ __launch_bounds__(256) void prep_all(
    const float* __restrict__ seq, unsigned short* __restrict__ seq_bf,
    const float* __restrict__ Wi, const float* __restrict__ Wu,
    const float* __restrict__ Wv, const float* __restrict__ Wz,
    const float* __restrict__ Wo, const float* __restrict__ Wg,
    unsigned short* __restrict__ Wit, unsigned short* __restrict__ Wuvzt,
    unsigned short* __restrict__ Wot, unsigned short* __restrict__ Wgt)
{
    const int b = blockIdx.x;
    if (b < 12288) {
        const size_t i = ((size_t)b * 256 + threadIdx.x) * 4;
        float4 v = *(const float4*)(seq + i);
        ushort4 o;
        o.x = f2bf(v.x); o.y = f2bf(v.y); o.z = f2bf(v.z); o.w = f2bf(v.w);
        *(ushort4*)(seq_bf + i) = o;
        return;
    }
    const int bb = b - 12288;
    const float* W;
    unsigned short* Wt;
    int K, N, t;
    if (bb < 576)       { W = Wi; Wt = Wit;  K = 768;  N = 768;  t = bb; }
    else if (bb < 1728) { W = Wu; Wt = Wuvzt;                        K = 768; N = 1536; t = bb - 576; }
    else if (bb < 2880) { W = Wv; Wt = Wuvzt + (size_t)1536 * 768;   K = 768; N = 1536; t = bb - 1728; }
    else if (bb < 2976) { W = Wz; Wt = Wuvzt + (size_t)3072 * 768;   K = 768; N = 128;  t = bb - 2880; }
    else if (bb < 4128) { W = Wo; Wt = Wot;  K = 1536; N = 768;  t = bb - 2976; }
    else                { W = Wg; Wt = Wgt;  K = 1536; N = 768;  t = bb - 4128; }
    const int nbx = N >> 5;
    const int kb = (t / nbx) * 32, nb = (t % nbx) * 32;

    __shared__ float tile[32][33];
    const int tx = threadIdx.x & 31, ty = threadIdx.x >> 5;
#pragma unroll
    for (int r = 0; r < 4; ++r)
        tile[ty + 8 * r][tx] = W[(size_t)(kb + ty + 8 * r) * N + nb + tx];
    __syncthreads();
#pragma unroll
    for (int r = 0; r < 4; ++r)
        Wt[(size_t)(nb + ty + 8 * r) * K + kb + tx] = f2bf(tile[tx][ty + 8 * r]);
}

// LayerNorm over 768, bf16 in/out, fp32 stats. grid = 16384 rows.
__global__ __launch_bounds__(256) void ln_bf16(
    const unsigned short* __restrict__ in, const float* __restrict__ g,
    const float* __restrict__ b, unsigned short* __restrict__ out)
{
    const int row = blockIdx.x;
    const unsigned short* p = in + (size_t)row * 768;
    const int tid = threadIdx.x;
    float v0 = bf2f(p[tid]), v1 = bf2f(p[tid + 256]), v2 = bf2f(p[tid + 512]);
    float s = v0 + v1 + v2;
    float q = v0 * v0 + v1 * v1 + v2 * v2;
#pragma unroll
    for (int off = 32; off; off >>= 1) {
        s += __shfl_xor(s, off);
        q += __shfl_xor(q, off);
    }
    __shared__ float ss[4], qq[4];
    const int wid = tid >> 6, lane = tid & 63;
    if (lane == 0) { ss[wid] = s; qq[wid] = q; }
    __syncthreads();
    s = ss[0] + ss[1] + ss[2] + ss[3];
    q = qq[0] + qq[1] + qq[2] + qq[3];
    const float mu  = s * (1.0f / 768.0f);
    const float var = q * (1.0f / 768.0f) - mu * mu;
    const float inv = rsqrtf(var + 1e-5f);
    unsigned short* o = out + (size_t)row * 768;
    o[tid]       = f2bf((v0 - mu) * inv * g[tid]       + b[tid]);
    o[tid + 256] = f2bf((v1 - mu) * inv * g[tid + 256] + b[tid + 256]);
    o[tid + 512] = f2bf((v2 - mu) * inv * g[tid + 512] + b[tid + 512]);
}

// Merged Q/K affine + q_pos. One wave per row (4 rows/block, grid 4096).
__global__ __launch_bounds__(256) void qk_prep(
    const float* __restrict__ Z, const float* __restrict__ gamma,
    const float* __restrict__ beta, const float* __restrict__ ep,
    float* __restrict__ qpos,
    unsigned short* __restrict__ Qb, unsigned short* __restrict__ Kb)
{
    const int tid = threadIdx.x;
    const int lane = tid & 63;
    const int wid = tid >> 6;
    const int row = blockIdx.x * 4 + wid;
    const float z0 = Z[(size_t)row * 128 + lane];
    const float z1 = Z[(size_t)row * 128 + 64 + lane];
    Qb[(size_t)row * 128 + lane]      = f2bf(z0 * gamma[lane]       + beta[lane]);
    Qb[(size_t)row * 128 + 64 + lane] = f2bf(z1 * gamma[64 + lane]  + beta[64 + lane]);
    Kb[(size_t)row * 128 + lane]      = f2bf(z0 * gamma[256 + lane]      + beta[256 + lane]);
    Kb[(size_t)row * 128 + 64 + lane] = f2bf(z1 * gamma[256 + 64 + lane] + beta[256 + 64 + lane]);
    const float q0 = z0 * gamma[128 + lane] + beta[128 + lane];
    const float q1 = z1 * gamma[192 + lane] + beta[192 + lane];
#pragma unroll
    for (int p = 0; p < 11; ++p) {
        float s = q0 * ep[p * 128 + lane] + q1 * ep[p * 128 + 64 + lane];
#pragma unroll
        for (int off = 32; off; off >>= 1) s += __shfl_xor(s, off);
        if (lane == 0) qpos[(size_t)row * 11 + p] = s;
    }
}

// ---------------------------------------------------------------------------
extern "C" void kernel_launch(void* const* d_in, const int* in_sizes, int n_in,
                              void* d_out, int out_size, void* d_ws, size_t ws_size,
                              hipStream_t stream)
{
    const float* seq    = (const float*)d_in[0];
    const float* W_init = (const float*)d_in[3];
    const float* b_init = (const float*)d_in[4];
    const float* ln_g   = (const float*)d_in[5];
    const float* ln_b   = (const float*)d_in[6];
    const float* W_u    = (const float*)d_in[7];
    const float* b_u    = (const float*)d_in[8];
    const float* W_v    = (const float*)d_in[9];
    const float* b_v    = (const float*)d_in[10];
    const float* W_z    = (const float*)d_in[11];
    const float* b_z    = (const float*)d_in[12];
    const float* gamma  = (const float*)d_in[13];
    const float* beta   = (const float*)d_in[14];
    const float* embed  = (const float*)d_in[15];
    const float* W_out  = (const float*)d_in[16];
    const float* b_out  = (const float*)d_in[17];
    const float* W_gate = (const float*)d_in[18];
    const float* b_gate = (const float*)d_in[19];
    float* out = (float*)d_out;

    // workspace (~299 MiB)
    char* ws = (char*)d_ws;
    float* Z    = (float*)ws;                     ws += (size_t)16384 * 128 * 4;
    float* qpos = (float*)ws;                     ws += (size_t)16384 * 11 * 4;
    float* part = (float*)ws;                     ws += (size_t)16384 * 32 * 4;
    float* inv  = (float*)ws;                     ws += (size_t)16384 * 4;
    unsigned short* seq_bf = (unsigned short*)ws; ws += (size_t)16384 * 768 * 2;
    unsigned short* G_bf   = (unsigned short*)ws; ws += (size_t)16384 * 768 * 2;
    unsigned short* x_bf   = (unsigned short*)ws; ws += (size_t)16384 * 768 * 2;
    unsigned short* U_bf   = (unsigned short*)ws; ws += (size_t)16384 * 1536 * 2;
    unsigned short* Vt     = (unsigned short*)ws; ws += (size_t)16384 * 1536 * 2;
    unsigned short* out_bf = (unsigned short*)ws; ws += (size_t)16384 * 768 * 2;
    unsigned short* Qb     = (unsigned short*)ws; ws += (size_t)16384 * 128 * 2;
    unsigned short* Kb     = (unsigned short*)ws; ws += (size_t)16384 * 128 * 2;
    unsigned short* E      = (unsigned short*)ws; ws += (size_t)8 * 2048 * 2048 * 2;
    unsigned short* Wit    = (unsigned short*)ws; ws += (size_t)768 * 768 * 2;
    unsigned short* Wuvzt  = (unsigned short*)ws; ws += (size_t)3200 * 768 * 2;
    unsigned short* Wot    = (unsigned short*)ws; ws += (size_t)768 * 1536 * 2;
    unsigned short* Wgt    = (unsigned short*)ws; ws += (size_t)768 * 1536 * 2;

    const dim3 b256(256);

    // 0. all input prep (seq conversion + 6 weight transposes), one launch
    prep_all<<<17568, b256, 0, stream>>>(seq, seq_bf,
                                         W_init, W_u, W_v, W_z, W_out, W_gate,
                                         Wit, Wuvzt, Wot, Wgt);

    // 1. G_bf = bf16(seq @ W_init + b_init)         [cx=6: full-x rows]
    mfma_gemm<2, false, 4><<<dim3(6, 128), b256, 0, stream>>>(
        seq_bf, 768, 0, Wit, 768, 0, nullptr, nullptr,
        b_init, nullptr, nullptr, 0, nullptr, G_bf, 0, nullptr, 768, 768, 6);
    // 2. x_bf = LN(G_bf)
    ln_bf16<<<16384, b256, 0, stream>>>(G_bf, ln_g, ln_b, x_bf);
    // 3. merged U | Vt | Z                           [MW=6, cx=25]
    mfma_gemm<8, false, 6><<<dim3(25, 128), b256, 0, stream>>>(
        x_bf, 768, 0, Wuvzt, 768, 0, nullptr, nullptr,
        b_u, b_v, b_z, 0, Z, U_bf, 0, Vt, 3200, 768, 25);
    // 4. q_pos + Qb/Kb (one launch, one Z read)
    qk_prep<<<4096, b256, 0, stream>>>(Z, gamma, beta, embed, qpos, Qb, Kb);

    // 5. attention; softmax fused (exp + rowsum inv) [MW=5, cx=8: 8x4 chunks]
    mfma_gemm<1, false, 5><<<dim3(16, 16, 8), b256, 0, stream>>>(
        Qb, 128, 2048L * 128, Kb, 128, 2048L * 128,
        nullptr, nullptr, nullptr, nullptr,
        qpos, 2048L * 11, part,
        E, 2048L * 2048, nullptr, 2048, 128, 8);
    reduce_inv<<<64, b256, 0, stream>>>(part, inv);
    // PV: Ub = bf16(E @ Vt * inv * U)                [MW=5, cx=6: 6x4 chunks]
    mfma_gemm<0, false, 5><<<dim3(12, 16, 8), b256, 0, stream>>>(
        E, 2048, 2048L * 2048, Vt, 2048, 1536L * 2048,
        nullptr, nullptr, nullptr, nullptr, nullptr, 0, inv,
        U_bf, 2048L * 1536, nullptr, 1536, 2048, 6);

    // 6. out = UV @ W_out + b_out (fp32 -> d_out, bf16 -> out_bf)
    mfma_gemm<6, false, 4><<<dim3(6, 128), b256, 0, stream>>>(
        U_bf, 1536, 0, Wot, 1536, 0, nullptr, nullptr,
        b_out, nullptr, nullptr, 0, nullptr, out, 0, out_bf, 768, 1536, 6);
    // 7. fused gate: g = sig(out_pre@Wg1 + seq@Wg2 + b); out = g*out + (1-g)*seq
    mfma_gemm<7, true, 4><<<dim3(6, 128), b256, 0, stream>>>(
        out_bf, 768, 0, Wgt, 1536, 0, seq_bf, Wgt + 768,
        b_gate, nullptr, seq, 0, nullptr, out, 0, nullptr, 768, 768, 6);
}

// Round 8
// 755.685 us; speedup vs baseline: 1.1746x; 1.1746x over previous
//
#include <hip/hip_runtime.h>
#include <math.h>

// GAU block. N=8, S=2048, D=768, DK=128, 2D=1536. NS=16384 rows.
// Round 14: recover from the round-13 MW=5 spill disaster. Evidence: MW=5
// dispatches ran VGPR_Count=48 < 64-reg accumulator floor -> acc spilled to
// scratch (FETCH +60MB, WRITE +20MB, MfmaUtil 29->14.7, dur 147->284us).
// MW=4 (VGPR 60, zero spill) is the proven configuration; "occupancy
// under-asked" is falsified. This round = round 12 (718.9us) + 2D XCD
// chunking ONLY (the one r13 lever left unmeasured; isolated A/B vs r12's
// 1D chunking: PV per-XCD working set 7MB -> 5MB vs 4MB L2).

typedef __bf16 bf16x8 __attribute__((ext_vector_type(8)));
typedef float  f32x4  __attribute__((ext_vector_type(4)));

__device__ __forceinline__ float silu_f(float v) { return v / (1.0f + __expf(-v)); }
__device__ __forceinline__ float sigmoid_f(float v) { return 1.0f / (1.0f + __expf(-v)); }

__device__ __forceinline__ unsigned short f2bf(float f) {
    union { float f; unsigned u; } v; v.f = f;
    unsigned r = v.u + 0x7fff + ((v.u >> 16) & 1);
    return (unsigned short)(r >> 16);
}
__device__ __forceinline__ float bf2f(unsigned short h) {
    union { unsigned u; float f; } v; v.u = ((unsigned)h) << 16; return v.f;
}

__device__ __forceinline__ void gload_lds16(const void* g, void* l) {
    __builtin_amdgcn_global_load_lds((const __attribute__((address_space(1))) char*)g,
                                     (__attribute__((address_space(3))) char*)l, 16, 0, 0);
}

// XCD-aware 2D-chunk bijective swizzle. Original flat index o: XCD = o&7
// (HW round-robin). XCD k owns a (cx x cy) tile-rectangle of the grid;
// requires cx | gx and 8/(gx/cx) | gy (true for every launch here).
__device__ __forceinline__ void xcd_swizzle(int& bx, int& by, int cx) {
    const int gx = gridDim.x;
    const int o  = by * gx + bx;
    const int c  = (gx * (int)gridDim.y) >> 3;  // blocks per XCD
    const int k  = o & 7;                       // XCD id
    const int j  = o >> 3;                      // ordinal within XCD
    const int nkx = gx / cx;                    // chunk columns
    const int cy  = c / cx;
    bx = (k % nkx) * cx + (j % cx);
    by = (k / nkx) * cy + (j / cx);
}

// ---------------------------------------------------------------------------
// bf16 MFMA GEMM: acc[M,N] = A[M,K] @ Bt[N,K]^T (+2nd pass if DUAL).
// 128x128 tile, BK=64, 256 thr / 4 waves 2x2, each wave 4x4 of 16x16x32.
// LDS rows hold 8 16B slots, stored at slot p = s ^ (r&7) -> 2-way reads.
// MW = min waves per EU. MW=4 is the no-spill sweet spot (VGPR 60); MW>=5
// caps VGPR below the 64-reg accumulator -> scratch spills (r13 evidence).
// Epilogues: 0 PV / 1 QK / 2 BIAS / 6 OUT / 7 GATE / 8 UVZ (see r12 notes).
// ---------------------------------------------------------------------------
template <int EPI, bool DUAL, int MW>
__global__ __launch_bounds__(256, MW) void mfma_gemm(
    const unsigned short* __restrict__ A,  int lda, long sA,
    const unsigned short* __restrict__ Bt, int ldb, long sB,
    const unsigned short* __restrict__ A2,
    const unsigned short* __restrict__ Bt2,
    const float* __restrict__ bias,
    const float* __restrict__ bias2,
    const float* __restrict__ aux, long sAux,
    float* __restrict__ aux2,
    void* __restrict__ P0, long sP0,
    void* __restrict__ P1,
    int N, int K, int swz_cx)
{
    __shared__ unsigned short As[128 * 64];
    __shared__ unsigned short Bs[128 * 64];
    const int tid  = threadIdx.x;
    const int lane = tid & 63;
    const int wave = tid >> 6;
    const int z    = blockIdx.z;
    int bx = blockIdx.x, by = blockIdx.y;
    xcd_swizzle(bx, by, swz_cx);
    const int row0 = by * 128;
    const int col0 = bx * 128;

    int c_r[4], c_g[4];
    unsigned short* alp[4];
    unsigned short* blp[4];
#pragma unroll
    for (int ci = 0; ci < 4; ++ci) {
        const int c = ci * 256 + tid;
        const int r = c >> 3;
        c_r[ci] = r;
        c_g[ci] = (c & 7) ^ (r & 7);   // global slot fetched into LDS pos c
        alp[ci] = &As[c * 8];
        blp[ci] = &Bs[c * 8];
    }

    const int wr = (wave >> 1) * 64;
    const int wc = (wave & 1) * 64;
    const int fm  = lane & 15;
    const int kbi = lane >> 4;
    const int er  = kbi * 4;

    int aoff[2][4], boff[2][4];
#pragma unroll
    for (int b = 0; b < 2; ++b)
#pragma unroll
        for (int i = 0; i < 4; ++i) {
            const int r = wr + i * 16 + fm;
            aoff[b][i] = r * 64 + (((b * 4 + kbi) ^ (r & 7)) * 8);
            const int n = wc + i * 16 + fm;
            boff[b][i] = n * 64 + (((b * 4 + kbi) ^ (n & 7)) * 8);
        }

    f32x4 acc[4][4];
#pragma unroll
    for (int i = 0; i < 4; ++i)
#pragma unroll
        for (int j = 0; j < 4; ++j) acc[i][j] = (f32x4){0.f, 0.f, 0.f, 0.f};

    const int npass = DUAL ? 2 : 1;
    for (int pass = 0; pass < npass; ++pass) {
        const unsigned short* Ab = (pass ? A2  : A)  + (size_t)z * sA;
        const unsigned short* Bb = (pass ? Bt2 : Bt) + (size_t)z * sB;
        const unsigned short* ag[4];
        const unsigned short* bg[4];
#pragma unroll
        for (int ci = 0; ci < 4; ++ci) {
            ag[ci] = Ab + (size_t)(row0 + c_r[ci]) * lda + c_g[ci] * 8;
            bg[ci] = Bb + (size_t)(col0 + c_r[ci]) * ldb + c_g[ci] * 8;
        }
        for (int k0 = 0; k0 < K; k0 += 64) {
#pragma unroll
            for (int ci = 0; ci < 4; ++ci) { gload_lds16(ag[ci], alp[ci]); ag[ci] += 64; }
#pragma unroll
            for (int ci = 0; ci < 4; ++ci) { gload_lds16(bg[ci], blp[ci]); bg[ci] += 64; }
            __syncthreads();
#pragma unroll
            for (int b = 0; b < 2; ++b) {
                bf16x8 a[4], bb[4];
#pragma unroll
                for (int i = 0; i < 4; ++i) a[i]  = *(const bf16x8*)&As[aoff[b][i]];
#pragma unroll
                for (int j = 0; j < 4; ++j) bb[j] = *(const bf16x8*)&Bs[boff[b][j]];
#pragma unroll
                for (int i = 0; i < 4; ++i)
#pragma unroll
                    for (int j = 0; j < 4; ++j)
                        acc[i][j] = __builtin_amdgcn_mfma_f32_16x16x32_bf16(
                            a[i], bb[j], acc[i][j], 0, 0, 0);
            }
            __syncthreads();
        }
    }

    if (EPI == 0) {
        unsigned short* Ub = (unsigned short*)P0 + (size_t)z * sP0;
        const float* inv = aux2 + (z << 11);
#pragma unroll
        for (int i = 0; i < 4; ++i)
#pragma unroll
            for (int j = 0; j < 4; ++j) {
                const int m0 = row0 + wr + i * 16 + er;
                const int n  = col0 + wc + j * 16 + fm;
#pragma unroll
                for (int reg = 0; reg < 4; ++reg) {
                    const size_t idx = (size_t)(m0 + reg) * N + n;
                    Ub[idx] = f2bf(acc[i][j][reg] * inv[m0 + reg] * bf2f(Ub[idx]));
                }
            }
    } else if (EPI == 1) {
        const float* qb = aux + (size_t)z * sAux;
        unsigned short* Eb = (unsigned short*)P0 + (size_t)z * sP0;
#pragma unroll
        for (int i = 0; i < 4; ++i) {
            float rs[4] = {0.f, 0.f, 0.f, 0.f};
#pragma unroll
            for (int j = 0; j < 4; ++j) {
                const int n = col0 + wc + j * 16 + fm;
#pragma unroll
                for (int reg = 0; reg < 4; ++reg) {
                    const int m = row0 + wr + i * 16 + er + reg;
                    int d = n - m;
                    d = d < -5 ? -5 : (d > 5 ? 5 : d);
                    const float v =
                        __expf((acc[i][j][reg] + qb[m * 11 + d + 5]) * 0.0625f);
                    const unsigned short h = f2bf(v);
                    Eb[(size_t)m * N + n] = h;
                    rs[reg] += bf2f(h);
                }
            }
#pragma unroll
            for (int reg = 0; reg < 4; ++reg) {
                float s = rs[reg];
                s += __shfl_xor(s, 1); s += __shfl_xor(s, 2);
                s += __shfl_xor(s, 4); s += __shfl_xor(s, 8);
                if (fm == 0) {
                    const int m = row0 + wr + i * 16 + er + reg;
                    aux2[((size_t)(z * 2048 + m)) * 32 + bx * 2 + (wave & 1)] = s;
                }
            }
        }
    } else if (EPI == 2) {
        unsigned short* Cb = (unsigned short*)P0;
#pragma unroll
        for (int j = 0; j < 4; ++j) {
            const int n = col0 + wc + j * 16 + fm;
            const float bb = bias[n];
#pragma unroll
            for (int i = 0; i < 4; ++i) {
                const int m0 = row0 + wr + i * 16 + er;
#pragma unroll
                for (int reg = 0; reg < 4; ++reg)
                    Cb[(size_t)(m0 + reg) * N + n] = f2bf(acc[i][j][reg] + bb);
            }
        }
    } else if (EPI == 6) {
        float* Of = (float*)P0;
        unsigned short* Ob = (unsigned short*)P1;
#pragma unroll
        for (int j = 0; j < 4; ++j) {
            const int n = col0 + wc + j * 16 + fm;
            const float bb = bias[n];
#pragma unroll
            for (int i = 0; i < 4; ++i) {
                const int m0 = row0 + wr + i * 16 + er;
#pragma unroll
                for (int reg = 0; reg < 4; ++reg) {
                    const float v = acc[i][j][reg] + bb;
                    const size_t idx = (size_t)(m0 + reg) * N + n;
                    Of[idx] = v;
                    Ob[idx] = f2bf(v);
                }
            }
        }
    } else if (EPI == 7) {
        float* Of = (float*)P0;
        const float* res = aux;
#pragma unroll
        for (int j = 0; j < 4; ++j) {
            const int n = col0 + wc + j * 16 + fm;
            const float bb = bias[n];
#pragma unroll
            for (int i = 0; i < 4; ++i) {
                const int m0 = row0 + wr + i * 16 + er;
#pragma unroll
                for (int reg = 0; reg < 4; ++reg) {
                    const float g = sigmoid_f(acc[i][j][reg] + bb);
                    const size_t idx = (size_t)(m0 + reg) * N + n;
                    Of[idx] = g * Of[idx] + (1.0f - g) * res[idx];
                }
            }
        }
    } else {  // EPI 8: merged U | Vt | Z — block-uniform on bx
        if (bx < 12) {
            unsigned short* Ub = (unsigned short*)P0;
#pragma unroll
            for (int j = 0; j < 4; ++j) {
                const int n = col0 + wc + j * 16 + fm;
                const float bb = bias[n];
#pragma unroll
                for (int i = 0; i < 4; ++i) {
                    const int m0 = row0 + wr + i * 16 + er;
#pragma unroll
                    for (int reg = 0; reg < 4; ++reg)
                        Ub[(size_t)(m0 + reg) * 1536 + n] =
                            f2bf(silu_f(acc[i][j][reg] + bb));
                }
            }
        } else if (bx < 24) {
            unsigned short* Vt = (unsigned short*)P1;
#pragma unroll
            for (int j = 0; j < 4; ++j) {
                const int n = col0 + wc + j * 16 + fm;
                const float bb = bias2[n - 1536];
#pragma unroll
                for (int i = 0; i < 4; ++i) {
                    const int m0 = row0 + wr + i * 16 + er;
                    const int bat = m0 >> 11;
                    const int sl  = m0 & 2047;
                    unsigned short t[4];
#pragma unroll
                    for (int reg = 0; reg < 4; ++reg)
                        t[reg] = f2bf(silu_f(acc[i][j][reg] + bb));
                    *(ushort4*)(Vt + (size_t)bat * 1536 * 2048
                                + (size_t)(n - 1536) * 2048 + sl) = *(const ushort4*)t;
                }
            }
        } else {
            float* Zf = aux2;
#pragma unroll
            for (int j = 0; j < 4; ++j) {
                const int n = col0 + wc + j * 16 + fm;
                const float bb = aux[n - 3072];
#pragma unroll
                for (int i = 0; i < 4; ++i) {
                    const int m0 = row0 + wr + i * 16 + er;
#pragma unroll
                    for (int reg = 0; reg < 4; ++reg)
                        Zf[(size_t)(m0 + reg) * 128 + (n - 3072)] =
                            silu_f(acc[i][j][reg] + bb);
                }
            }
        }
    }
}

// rowsum inverse: inv[r] = 1 / sum_k part[r][k], r in [0,16384)
__global__ __launch_bounds__(256) void reduce_inv(
    const float* __restrict__ part, float* __restrict__ inv)
{
    const int r = blockIdx.x * 256 + threadIdx.x;
    const float4* p = (const float4*)(part + (size_t)r * 32);
    float s = 0.f;
#pragma unroll
    for (int k = 0; k < 8; ++k) {
        float4 v = p[k];
        s += v.x + v.y + v.z + v.w;
    }
    inv[r] = 1.0f / s;
}

// All input prep in one launch. Flat grid:
// [0,12288)      : seq fp32 -> bf16 (4 elems/thread)
// [12288,12864)  : W_init -> Wit        (768x768)
// [12864,14016)  : W_u    -> Wuvzt      (768x1536)
// [14016,15168)  : W_v    -> Wuvzt+1536*768
// [15168,15264)  : W_z    -> Wuvzt+3072*768 (768x128)
// [15264,16416)  : W_out  -> Wot        (1536x768)
// [16416,17568)  : W_gate -> Wgt        (1536x768)
__global__ __launch_bounds__(256) void prep_all(
    const float* __restrict__ seq, unsigned short* __restrict__ seq_bf,
    const float* __restrict__ Wi, const float* __restrict__ Wu,
    const float* __restrict__ Wv, const float* __restrict__ Wz,
    const float* __restrict__ Wo, const float* __restrict__ Wg,
    unsigned short* __restrict__ Wit, unsigned short* __restrict__ Wuvzt,
    unsigned short* __restrict__ Wot, unsigned short* __restrict__ Wgt)
{
    const int b = blockIdx.x;
    if (b < 12288) {
        const size_t i = ((size_t)b * 256 + threadIdx.x) * 4;
        float4 v = *(const float4*)(seq + i);
        ushort4 o;
        o.x = f2bf(v.x); o.y = f2bf(v.y); o.z = f2bf(v.z); o.w = f2bf(v.w);
        *(ushort4*)(seq_bf + i) = o;
        return;
    }
    const int bb = b - 12288;
    const float* W;
    unsigned short* Wt;
    int K, N, t;
    if (bb < 576)       { W = Wi; Wt = Wit;  K = 768;  N = 768;  t = bb; }
    else if (bb < 1728) { W = Wu; Wt = Wuvzt;                        K = 768; N = 1536; t = bb - 576; }
    else if (bb < 2880) { W = Wv; Wt = Wuvzt + (size_t)1536 * 768;   K = 768; N = 1536; t = bb - 1728; }
    else if (bb < 2976) { W = Wz; Wt = Wuvzt + (size_t)3072 * 768;   K = 768; N = 128;  t = bb - 2880; }
    else if (bb < 4128) { W = Wo; Wt = Wot;  K = 1536; N = 768;  t = bb - 2976; }
    else                { W = Wg; Wt = Wgt;  K = 1536; N = 768;  t = bb - 4128; }
    const int nbx = N >> 5;
    const int kb = (t / nbx) * 32, nb = (t % nbx) * 32;

    __shared__ float tile[32][33];
    const int tx = threadIdx.x & 31, ty = threadIdx.x >> 5;
#pragma unroll
    for (int r = 0; r < 4; ++r)
        tile[ty + 8 * r][tx] = W[(size_t)(kb + ty + 8 * r) * N + nb + tx];
    __syncthreads();
#pragma unroll
    for (int r = 0; r < 4; ++r)
        Wt[(size_t)(nb + ty + 8 * r) * K + kb + tx] = f2bf(tile[tx][ty + 8 * r]);
}

// LayerNorm over 768, bf16 in/out, fp32 stats. grid = 16384 rows.
__global__ __launch_bounds__(256) void ln_bf16(
    const unsigned short* __restrict__ in, const float* __restrict__ g,
    const float* __restrict__ b, unsigned short* __restrict__ out)
{
    const int row = blockIdx.x;
    const unsigned short* p = in + (size_t)row * 768;
    const int tid = threadIdx.x;
    float v0 = bf2f(p[tid]), v1 = bf2f(p[tid + 256]), v2 = bf2f(p[tid + 512]);
    float s = v0 + v1 + v2;
    float q = v0 * v0 + v1 * v1 + v2 * v2;
#pragma unroll
    for (int off = 32; off; off >>= 1) {
        s += __shfl_xor(s, off);
        q += __shfl_xor(q, off);
    }
    __shared__ float ss[4], qq[4];
    const int wid = tid >> 6, lane = tid & 63;
    if (lane == 0) { ss[wid] = s; qq[wid] = q; }
    __syncthreads();
    s = ss[0] + ss[1] + ss[2] + ss[3];
    q = qq[0] + qq[1] + qq[2] + qq[3];
    const float mu  = s * (1.0f / 768.0f);
    const float var = q * (1.0f / 768.0f) - mu * mu;
    const float inv = rsqrtf(var + 1e-5f);
    unsigned short* o = out + (size_t)row * 768;
    o[tid]       = f2bf((v0 - mu) * inv * g[tid]       + b[tid]);
    o[tid + 256] = f2bf((v1 - mu) * inv * g[tid + 256] + b[tid + 256]);
    o[tid + 512] = f2bf((v2 - mu) * inv * g[tid + 512] + b[tid + 512]);
}

// Merged Q/K affine + q_pos. One wave per row (4 rows/block, grid 4096).
__global__ __launch_bounds__(256) void qk_prep(
    const float* __restrict__ Z, const float* __restrict__ gamma,
    const float* __restrict__ beta, const float* __restrict__ ep,
    float* __restrict__ qpos,
    unsigned short* __restrict__ Qb, unsigned short* __restrict__ Kb)
{
    const int tid = threadIdx.x;
    const int lane = tid & 63;
    const int wid = tid >> 6;
    const int row = blockIdx.x * 4 + wid;
    const float z0 = Z[(size_t)row * 128 + lane];
    const float z1 = Z[(size_t)row * 128 + 64 + lane];
    Qb[(size_t)row * 128 + lane]      = f2bf(z0 * gamma[lane]       + beta[lane]);
    Qb[(size_t)row * 128 + 64 + lane] = f2bf(z1 * gamma[64 + lane]  + beta[64 + lane]);
    Kb[(size_t)row * 128 + lane]      = f2bf(z0 * gamma[256 + lane]      + beta[256 + lane]);
    Kb[(size_t)row * 128 + 64 + lane] = f2bf(z1 * gamma[256 + 64 + lane] + beta[256 + 64 + lane]);
    const float q0 = z0 * gamma[128 + lane] + beta[128 + lane];
    const float q1 = z1 * gamma[192 + lane] + beta[192 + lane];
#pragma unroll
    for (int p = 0; p < 11; ++p) {
        float s = q0 * ep[p * 128 + lane] + q1 * ep[p * 128 + 64 + lane];
#pragma unroll
        for (int off = 32; off; off >>= 1) s += __shfl_xor(s, off);
        if (lane == 0) qpos[(size_t)row * 11 + p] = s;
    }
}

// ---------------------------------------------------------------------------
extern "C" void kernel_launch(void* const* d_in, const int* in_sizes, int n_in,
                              void* d_out, int out_size, void* d_ws, size_t ws_size,
                              hipStream_t stream)
{
    const float* seq    = (const float*)d_in[0];
    const float* W_init = (const float*)d_in[3];
    const float* b_init = (const float*)d_in[4];
    const float* ln_g   = (const float*)d_in[5];
    const float* ln_b   = (const float*)d_in[6];
    const float* W_u    = (const float*)d_in[7];
    const float* b_u    = (const float*)d_in[8];
    const float* W_v    = (const float*)d_in[9];
    const float* b_v    = (const float*)d_in[10];
    const float* W_z    = (const float*)d_in[11];
    const float* b_z    = (const float*)d_in[12];
    const float* gamma  = (const float*)d_in[13];
    const float* beta   = (const float*)d_in[14];
    const float* embed  = (const float*)d_in[15];
    const float* W_out  = (const float*)d_in[16];
    const float* b_out  = (const float*)d_in[17];
    const float* W_gate = (const float*)d_in[18];
    const float* b_gate = (const float*)d_in[19];
    float* out = (float*)d_out;

    // workspace (~299 MiB)
    char* ws = (char*)d_ws;
    float* Z    = (float*)ws;                     ws += (size_t)16384 * 128 * 4;
    float* qpos = (float*)ws;                     ws += (size_t)16384 * 11 * 4;
    float* part = (float*)ws;                     ws += (size_t)16384 * 32 * 4;
    float* inv  = (float*)ws;                     ws += (size_t)16384 * 4;
    unsigned short* seq_bf = (unsigned short*)ws; ws += (size_t)16384 * 768 * 2;
    unsigned short* G_bf   = (unsigned short*)ws; ws += (size_t)16384 * 768 * 2;
    unsigned short* x_bf   = (unsigned short*)ws; ws += (size_t)16384 * 768 * 2;
    unsigned short* U_bf   = (unsigned short*)ws; ws += (size_t)16384 * 1536 * 2;
    unsigned short* Vt     = (unsigned short*)ws; ws += (size_t)16384 * 1536 * 2;
    unsigned short* out_bf = (unsigned short*)ws; ws += (size_t)16384 * 768 * 2;
    unsigned short* Qb     = (unsigned short*)ws; ws += (size_t)16384 * 128 * 2;
    unsigned short* Kb     = (unsigned short*)ws; ws += (size_t)16384 * 128 * 2;
    unsigned short* E      = (unsigned short*)ws; ws += (size_t)8 * 2048 * 2048 * 2;
    unsigned short* Wit    = (unsigned short*)ws; ws += (size_t)768 * 768 * 2;
    unsigned short* Wuvzt  = (unsigned short*)ws; ws += (size_t)3200 * 768 * 2;
    unsigned short* Wot    = (unsigned short*)ws; ws += (size_t)768 * 1536 * 2;
    unsigned short* Wgt    = (unsigned short*)ws; ws += (size_t)768 * 1536 * 2;

    const dim3 b256(256);

    // 0. all input prep (seq conversion + 6 weight transposes), one launch
    prep_all<<<17568, b256, 0, stream>>>(seq, seq_bf,
                                         W_init, W_u, W_v, W_z, W_out, W_gate,
                                         Wit, Wuvzt, Wot, Wgt);

    // 1. G_bf = bf16(seq @ W_init + b_init)         [cx=6]
    mfma_gemm<2, false, 4><<<dim3(6, 128), b256, 0, stream>>>(
        seq_bf, 768, 0, Wit, 768, 0, nullptr, nullptr,
        b_init, nullptr, nullptr, 0, nullptr, G_bf, 0, nullptr, 768, 768, 6);
    // 2. x_bf = LN(G_bf)
    ln_bf16<<<16384, b256, 0, stream>>>(G_bf, ln_g, ln_b, x_bf);
    // 3. merged U | Vt | Z                           [MW=6, cx=25]
    mfma_gemm<8, false, 6><<<dim3(25, 128), b256, 0, stream>>>(
        x_bf, 768, 0, Wuvzt, 768, 0, nullptr, nullptr,
        b_u, b_v, b_z, 0, Z, U_bf, 0, Vt, 3200, 768, 25);
    // 4. q_pos + Qb/Kb (one launch, one Z read)
    qk_prep<<<4096, b256, 0, stream>>>(Z, gamma, beta, embed, qpos, Qb, Kb);

    // 5. attention; softmax fused (exp + rowsum inv) [MW=4, cx=8: 8x4 chunks]
    mfma_gemm<1, false, 4><<<dim3(16, 16, 8), b256, 0, stream>>>(
        Qb, 128, 2048L * 128, Kb, 128, 2048L * 128,
        nullptr, nullptr, nullptr, nullptr,
        qpos, 2048L * 11, part,
        E, 2048L * 2048, nullptr, 2048, 128, 8);
    reduce_inv<<<64, b256, 0, stream>>>(part, inv);
    // PV: Ub = bf16(E @ Vt * inv * U)                [MW=4, cx=6: 6x4 chunks]
    mfma_gemm<0, false, 4><<<dim3(12, 16, 8), b256, 0, stream>>>(
        E, 2048, 2048L * 2048, Vt, 2048, 1536L * 2048,
        nullptr, nullptr, nullptr, nullptr, nullptr, 0, inv,
        U_bf, 2048L * 1536, nullptr, 1536, 2048, 6);

    // 6. out = UV @ W_out + b_out (fp32 -> d_out, bf16 -> out_bf)
    mfma_gemm<6, false, 4><<<dim3(6, 128), b256, 0, stream>>>(
        U_bf, 1536, 0, Wot, 1536, 0, nullptr, nullptr,
        b_out, nullptr, nullptr, 0, nullptr, out, 0, out_bf, 768, 1536, 6);
    // 7. fused gate: g = sig(out_pre@Wg1 + seq@Wg2 + b); out = g*out + (1-g)*seq
    mfma_gemm<7, true, 4><<<dim3(6, 128), b256, 0, stream>>>(
        out_bf, 768, 0, Wgt, 1536, 0, seq_bf, Wgt + 768,
        b_gate, nullptr, seq, 0, nullptr, out, 0, nullptr, 768, 768, 6);
}